// Round 1
// baseline (864.980 us; speedup 1.0000x reference)
//
#include <hip/hip_runtime.h>
#include <math.h>

#define H 28
#define N 784
#define B 32
#define T 25
#define NPAD 1024

// ---- numpy linspace replication (float64) ----
__device__ __forceinline__ double coord_r(int i) {
    // np.linspace(224, 0, 28): y[i] = i*delta + start, y[-1] = stop exactly
    if (i == H - 1) return 0.0;
    return 224.0 + (double)i * ((0.0 - 224.0) / 27.0);
}
__device__ __forceinline__ double coord_c(int j) {
    if (j == H - 1) return 224.0;
    return (double)j * (224.0 / 27.0);
}

// ============================================================
// Kernel 1: per-row sort of squared distances (f64, bitonic in LDS).
// Output transposed: d2s_t[k*N + i], sidx_t[k*N + i] (k = sorted pos).
// Tie order within equal-D2 groups provably does not affect DTM.
// ============================================================
__global__ void sort_d2_kernel(float* __restrict__ d2s_t,
                               unsigned short* __restrict__ sidx_t) {
    __shared__ double key[NPAD];
    __shared__ int    idx[NPAD];
    const int i   = blockIdx.x;
    const int tid = threadIdx.x;
    const int ri = i / H, ci = i % H;
    const double rri = coord_r(ri), cci = coord_c(ci);
    for (int j = tid; j < NPAD; j += 256) {
        if (j < N) {
            int rj = j / H, cj = j % H;
            double dr = rri - coord_r(rj);
            double dc = cci - coord_c(cj);
            key[j] = dr * dr + dc * dc;
        } else {
            key[j] = 1.0e300;
        }
        idx[j] = j;
    }
    __syncthreads();
    for (int k = 2; k <= NPAD; k <<= 1) {
        for (int j = k >> 1; j > 0; j >>= 1) {
            for (int a = tid; a < NPAD; a += 256) {
                int b = a ^ j;
                if (b > a) {
                    double ka = key[a], kb = key[b];
                    int    ia = idx[a], ib = idx[b];
                    bool gt = (ka > kb) || (ka == kb && ia > ib);
                    if (gt == ((a & k) == 0)) {
                        key[a] = kb; key[b] = ka;
                        idx[a] = ib; idx[b] = ia;
                    }
                }
            }
            __syncthreads();
        }
    }
    for (int j = tid; j < N; j += 256) {
        d2s_t[j * N + i]  = (float)key[j];
        sidx_t[j * N + i] = (unsigned short)idx[j];
    }
}

// ============================================================
// Kernel 2: DTM. block = mi*32 + b. Early-exit walk of sorted list.
// ============================================================
__global__ void dtm_kernel(const float* __restrict__ x,
                           const float* __restrict__ d2s_t,
                           const unsigned short* __restrict__ sidx_t,
                           float* __restrict__ fout) {
    __shared__ float lw[N];
    __shared__ float red[256];
    const int b  = blockIdx.x & 31;
    const int mi = blockIdx.x >> 5;
    const float m0 = mi ? 0.2f : 0.05f;
    const int tid = threadIdx.x;
    float s = 0.f;
    for (int i = tid; i < N; i += 256) {
        float v = x[b * N + i];
        lw[i] = v;
        s += v;
    }
    red[tid] = s;
    __syncthreads();
    for (int off = 128; off > 0; off >>= 1) {
        if (tid < off) red[tid] += red[tid + off];
        __syncthreads();
    }
    const float m0W = m0 * red[0];
    for (int i = tid; i < N; i += 256) {
        float cum = 0.f, acc = 0.f;
        for (int k = 0; k < N; ++k) {
            float d2  = d2s_t[k * N + i];
            int   id  = sidx_t[k * N + i];
            float swk = lw[id];
            float rem = m0W - cum;
            float contrib = fminf(fmaxf(rem, 0.f), swk);
            acc += contrib * d2;
            cum += swk;
            if (cum >= m0W) break;   // all later contribs are 0
        }
        fout[(mi * B + b) * N + i] = sqrtf(fmaxf(acc / m0W, 1e-12f));
    }
}

// ============================================================
// Kernel 3: PH0 (elder rule, stable (f,idx) order) + landscapes top-2.
// One block per (m0, batch) problem; union-find on thread 0 with
// path halving (root-equivalent to the reference's plain find).
// ============================================================
__device__ __forceinline__ int uf_find(short* parent, int u) {
    int x = u;
    int p = parent[x];
    while (p != x) {
        int gp = parent[p];
        parent[x] = (short)gp;  // path halving
        x = gp;
        p = parent[x];
    }
    return x;
}

__global__ void ph0_kernel(const float* __restrict__ fin,
                           float* __restrict__ feat) {
    __shared__ float skey[NPAD];
    __shared__ short sidx[NPAD];
    __shared__ float fv[N];
    __shared__ short parent[N];
    __shared__ short rank_[N];
    __shared__ short pd[N];
    const int prob = blockIdx.x;     // 0..63 = mi*32 + b
    const int tid  = threadIdx.x;
    const float* f = fin + prob * N;
    for (int j = tid; j < NPAD; j += 256) {
        float v = (j < N) ? f[j] : 3.0e38f;
        skey[j] = v;
        sidx[j] = (short)j;
        if (j < N) fv[j] = v;
    }
    __syncthreads();
    // stable bitonic argsort ascending by (f, idx)
    for (int k = 2; k <= NPAD; k <<= 1) {
        for (int j = k >> 1; j > 0; j >>= 1) {
            for (int a = tid; a < NPAD; a += 256) {
                int b2 = a ^ j;
                if (b2 > a) {
                    float ka = skey[a], kb = skey[b2];
                    short ia = sidx[a], ib = sidx[b2];
                    bool gt = (ka > kb) || (ka == kb && ia > ib);
                    if (gt == ((a & k) == 0)) {
                        skey[a] = kb; skey[b2] = ka;
                        sidx[a] = ib; sidx[b2] = ia;
                    }
                }
            }
            __syncthreads();
        }
    }
    for (int j = tid; j < N; j += 256) {
        rank_[sidx[j]] = (short)j;
        parent[j] = (short)j;
        pd[j]     = (short)j;
    }
    __syncthreads();
    if (tid == 0) {
        for (int t = 0; t < N; ++t) {
            int v   = sidx[t];
            int row = v / H, col = v % H;
            int  nbs[4] = { v - H, v + H, v - 1, v + 1 };
            bool val[4] = { row > 0, row < H - 1, col > 0, col < H - 1 };
            #pragma unroll
            for (int k4 = 0; k4 < 4; ++k4) {
                if (!val[k4]) continue;
                int nb = nbs[k4];
                if ((int)rank_[nb] >= t) continue;     // not yet processed
                int rv = uf_find(parent, v);
                int rn = uf_find(parent, nb);
                if (rn == rv) continue;
                float fn = fv[rn], fr = fv[rv];
                bool nw = (fn < fr) || (fn == fr && rn < rv);
                int w_ = nw ? rn : rv;
                int l_ = nw ? rv : rn;
                pd[l_]     = (short)v;
                parent[l_] = (short)w_;
            }
        }
        int vmax = (int)sidx[N - 1];
        int g = uf_find(parent, vmax);
        pd[g] = (short)vmax;
    }
    __syncthreads();
    // landscapes: tent[t,i] = relu(min(t - b_i, d_i - t)); top-2 over i
    const int wave = tid >> 6, lane = tid & 63;
    for (int t = wave; t < T; t += 4) {
        float tval = (t == T - 1) ? 80.0f : (1.0f + (float)t * (79.0f / 24.0f));
        float m1 = 0.f, m2 = 0.f;
        for (int i = lane; i < N; i += 64) {
            float bi = fv[i];
            float di = fv[(int)pd[i]];
            float tv = fminf(tval - bi, di - tval);
            tv = fmaxf(tv, 0.f);
            float lo = fminf(tv, m1);
            m1 = fmaxf(tv, m1);
            m2 = fmaxf(m2, lo);
        }
        #pragma unroll
        for (int off = 32; off > 0; off >>= 1) {
            float o1 = __shfl_down(m1, off, 64);
            float o2 = __shfl_down(m2, off, 64);
            float hi = fmaxf(m1, o1);
            float lo = fminf(m1, o1);
            m2 = fmaxf(fmaxf(m2, o2), lo);
            m1 = hi;
        }
        if (lane == 0) {
            feat[prob * 50 + t]     = m1;   // k=0
            feat[prob * 50 + T + t] = m2;   // k=1
        }
    }
}

// ============================================================
// Kernel 4: head. xc = [feat0@wg1.T+bg1 | feat1@wg2.T+bg2];
// signal = sum_b |xc|; out = relu(xc)@fc_w.T + fc_b.
// d_out = [out(320) | signal(100)]
// ============================================================
__global__ void head_kernel(const float* __restrict__ feat,
                            const float* __restrict__ wg1, const float* __restrict__ bg1,
                            const float* __restrict__ wg2, const float* __restrict__ bg2,
                            const float* __restrict__ fcw, const float* __restrict__ fcb,
                            float* __restrict__ out) {
    __shared__ float xc[B * 100];
    const int tid = threadIdx.x;
    for (int e = tid; e < B * 100; e += 256) {
        int b = e / 100, j = e % 100;
        const float* fp; const float* wrow; float bias;
        if (j < 50) { fp = feat + b * 50;       wrow = wg1 + j * 50;        bias = bg1[j]; }
        else        { fp = feat + (B + b) * 50; wrow = wg2 + (j - 50) * 50; bias = bg2[j - 50]; }
        float acc = bias;
        for (int q = 0; q < 50; ++q) acc += fp[q] * wrow[q];
        xc[e] = acc;
    }
    __syncthreads();
    for (int j = tid; j < 100; j += 256) {
        float s = 0.f;
        for (int b = 0; b < B; ++b) s += fabsf(xc[b * 100 + j]);
        out[320 + j] = s;
    }
    for (int e = tid; e < 320; e += 256) {
        int b = e / 10, o = e % 10;
        float acc = fcb[o];
        for (int j = 0; j < 100; ++j)
            acc += fmaxf(xc[b * 100 + j], 0.f) * fcw[o * 100 + j];
        out[e] = acc;
    }
}

extern "C" void kernel_launch(void* const* d_in, const int* in_sizes, int n_in,
                              void* d_out, int out_size, void* d_ws, size_t ws_size,
                              hipStream_t stream) {
    (void)in_sizes; (void)n_in; (void)out_size; (void)ws_size;
    const float* x   = (const float*)d_in[0];
    const float* wg1 = (const float*)d_in[1];
    const float* bg1 = (const float*)d_in[2];
    const float* wg2 = (const float*)d_in[3];
    const float* bg2 = (const float*)d_in[4];
    const float* fcw = (const float*)d_in[5];
    const float* fcb = (const float*)d_in[6];
    float* out = (float*)d_out;

    char* ws = (char*)d_ws;
    float*          d2s  = (float*)ws;                                   // N*N f32
    unsigned short* sidx = (unsigned short*)(ws + (size_t)N * N * 4);    // N*N u16
    float*          f    = (float*)(ws + (size_t)N * N * 6);             // 2*B*N f32
    float*          feat = f + 2 * B * N;                                // 2*B*50 f32

    sort_d2_kernel<<<dim3(N), dim3(256), 0, stream>>>(d2s, sidx);
    dtm_kernel<<<dim3(64), dim3(256), 0, stream>>>(x, d2s, sidx, f);
    ph0_kernel<<<dim3(64), dim3(256), 0, stream>>>(f, feat);
    head_kernel<<<dim3(1), dim3(256), 0, stream>>>(feat, wg1, bg1, wg2, bg2, fcw, fcb, out);
}

// Round 2
// 778.866 us; speedup vs baseline: 1.1106x; 1.1106x over previous
//
#include <hip/hip_runtime.h>
#include <math.h>

#define H 28
#define N 784
#define B 32
#define T 25
#define NPAD 1024

// ---- numpy linspace replication (float64) ----
__device__ __forceinline__ double coord_r(int i) {
    if (i == H - 1) return 0.0;
    return 224.0 + (double)i * ((0.0 - 224.0) / 27.0);
}
__device__ __forceinline__ double coord_c(int j) {
    if (j == H - 1) return 224.0;
    return (double)j * (224.0 / 27.0);
}

// ============================================================
// Kernel 1: per-row sort of squared distances (f64, bitonic in LDS).
// Output transposed: d2s_t[k*N + i], sidx_t[k*N + i].
// ============================================================
__global__ void sort_d2_kernel(float* __restrict__ d2s_t,
                               unsigned short* __restrict__ sidx_t) {
    __shared__ double key[NPAD];
    __shared__ int    idx[NPAD];
    const int i   = blockIdx.x;
    const int tid = threadIdx.x;
    const int ri = i / H, ci = i % H;
    const double rri = coord_r(ri), cci = coord_c(ci);
    for (int j = tid; j < NPAD; j += 256) {
        if (j < N) {
            int rj = j / H, cj = j % H;
            double dr = rri - coord_r(rj);
            double dc = cci - coord_c(cj);
            key[j] = dr * dr + dc * dc;
        } else {
            key[j] = 1.0e300;
        }
        idx[j] = j;
    }
    __syncthreads();
    for (int k = 2; k <= NPAD; k <<= 1) {
        for (int j = k >> 1; j > 0; j >>= 1) {
            for (int a = tid; a < NPAD; a += 256) {
                int b = a ^ j;
                if (b > a) {
                    double ka = key[a], kb = key[b];
                    int    ia = idx[a], ib = idx[b];
                    bool gt = (ka > kb) || (ka == kb && ia > ib);
                    if (gt == ((a & k) == 0)) {
                        key[a] = kb; key[b] = ka;
                        idx[a] = ib; idx[b] = ia;
                    }
                }
            }
            __syncthreads();
        }
    }
    for (int j = tid; j < N; j += 256) {
        d2s_t[j * N + i]  = (float)key[j];
        sidx_t[j * N + i] = (unsigned short)idx[j];
    }
}

// ============================================================
// Kernel 2: DTM with early-exit walk of sorted neighbor list.
// ============================================================
__global__ void dtm_kernel(const float* __restrict__ x,
                           const float* __restrict__ d2s_t,
                           const unsigned short* __restrict__ sidx_t,
                           float* __restrict__ fout) {
    __shared__ float lw[N];
    __shared__ float red[256];
    const int b  = blockIdx.x & 31;
    const int mi = blockIdx.x >> 5;
    const float m0 = mi ? 0.2f : 0.05f;
    const int tid = threadIdx.x;
    float s = 0.f;
    for (int i = tid; i < N; i += 256) {
        float v = x[b * N + i];
        lw[i] = v;
        s += v;
    }
    red[tid] = s;
    __syncthreads();
    for (int off = 128; off > 0; off >>= 1) {
        if (tid < off) red[tid] += red[tid + off];
        __syncthreads();
    }
    const float m0W = m0 * red[0];
    for (int i = tid; i < N; i += 256) {
        float cum = 0.f, acc = 0.f;
        for (int k = 0; k < N; ++k) {
            float d2  = d2s_t[k * N + i];
            int   id  = sidx_t[k * N + i];
            float swk = lw[id];
            float rem = m0W - cum;
            float contrib = fminf(fmaxf(rem, 0.f), swk);
            acc += contrib * d2;
            cum += swk;
            if (cum >= m0W) break;
        }
        fout[(mi * B + b) * N + i] = sqrtf(fmaxf(acc / m0W, 1e-12f));
    }
}

// ============================================================
// Kernel 3: PH0 via speculative batched Kruskal with direct-root
// labels + parallel relabel. Exactly replicates reference merge
// order: edges ordered by (rank of later endpoint, neighbor slot).
// ============================================================
__global__ void ph0_kernel(const float* __restrict__ fin,
                           float* __restrict__ feat) {
    __shared__ float skey[NPAD];
    __shared__ short sidx_s[NPAD];
    __shared__ float fv[N];
    __shared__ short rank_[N];
    __shared__ short root[N];
    __shared__ float rootf[N];
    __shared__ short pd[N];
    __shared__ unsigned short ev[1536];
    __shared__ unsigned short enb[1536];
    __shared__ int   tcnt[256];
    const int prob = blockIdx.x;
    const int tid  = threadIdx.x;
    const float* f = fin + prob * N;

    for (int j = tid; j < NPAD; j += 256) {
        float v = (j < N) ? f[j] : 3.0e38f;
        skey[j] = v;
        sidx_s[j] = (short)j;
        if (j < N) fv[j] = v;
    }
    __syncthreads();
    // stable bitonic argsort ascending by (f, idx)
    for (int k = 2; k <= NPAD; k <<= 1) {
        for (int j = k >> 1; j > 0; j >>= 1) {
            for (int a = tid; a < NPAD; a += 256) {
                int b2 = a ^ j;
                if (b2 > a) {
                    float ka = skey[a], kb = skey[b2];
                    short ia = sidx_s[a], ib = sidx_s[b2];
                    bool gt = (ka > kb) || (ka == kb && ia > ib);
                    if (gt == ((a & k) == 0)) {
                        skey[a] = kb; skey[b2] = ka;
                        sidx_s[a] = ib; sidx_s[b2] = ia;
                    }
                }
            }
            __syncthreads();
        }
    }
    for (int j = tid; j < N; j += 256) {
        int v = sidx_s[j];
        rank_[v]  = (short)j;
        root[j]   = (short)j;
        rootf[j]  = fv[j];
        pd[j]     = (short)j;
    }
    __syncthreads();

    // ---- build ordered compact edge list: key = (rank(v), k) ----
    // thread t owns ranks [t*4, t*4+4)
    int cnt = 0;
    #pragma unroll
    for (int rr = 0; rr < 4; ++rr) {
        int r = tid * 4 + rr;
        if (r < N) {
            int v = sidx_s[r];
            int row = v / H, col = v % H;
            if (row > 0     && (int)rank_[v - H] < r) cnt++;
            if (row < H - 1 && (int)rank_[v + H] < r) cnt++;
            if (col > 0     && (int)rank_[v - 1] < r) cnt++;
            if (col < H - 1 && (int)rank_[v + 1] < r) cnt++;
        }
    }
    tcnt[tid] = cnt;
    __syncthreads();
    for (int off = 1; off < 256; off <<= 1) {
        int v = tcnt[tid];
        if (tid >= off) v += tcnt[tid - off];
        __syncthreads();
        tcnt[tid] = v;
        __syncthreads();
    }
    const int m = tcnt[255];              // == 1512 for this grid
    int pos = tcnt[tid] - cnt;            // exclusive offset
    #pragma unroll
    for (int rr = 0; rr < 4; ++rr) {
        int r = tid * 4 + rr;
        if (r < N) {
            int v = sidx_s[r];
            int row = v / H, col = v % H;
            int nbs[4] = { v - H, v + H, v - 1, v + 1 };
            bool val[4] = { row > 0, row < H - 1, col > 0, col < H - 1 };
            #pragma unroll
            for (int k4 = 0; k4 < 4; ++k4) {
                if (val[k4] && (int)rank_[nbs[k4]] < r) {
                    ev[pos]  = (unsigned short)v;
                    enb[pos] = (unsigned short)nbs[k4];
                    pos++;
                }
            }
        }
    }
    __syncthreads();

    // ---- speculative batched Kruskal (all threads redundant) ----
    const int nbatch = (m + 7) >> 3;
    for (int bi = 0; bi < nbatch; ++bi) {
        const int base = bi * 8;
        // gather round 1: edge endpoints
        int va[8], na[8];
        #pragma unroll
        for (int e = 0; e < 8; ++e) {
            int idx = base + e;
            va[e] = (idx < m) ? (int)ev[idx]  : 0;
            na[e] = (idx < m) ? (int)enb[idx] : 0;
        }
        // gather round 2: roots + root f-values
        int ra[8], rb[8]; float fa[8], fb[8];
        #pragma unroll
        for (int e = 0; e < 8; ++e) {
            ra[e] = root[va[e]]; rb[e] = root[na[e]];
            fa[e] = rootf[va[e]]; fb[e] = rootf[na[e]];
        }
        // in-register sequential resolution (identical on all threads)
        int mL[8], mW[8], mD[8]; float mWf[8]; int nm = 0;
        #pragma unroll
        for (int e = 0; e < 8; ++e) {
            if (base + e >= m) continue;
            int a = ra[e], b = rb[e];
            float af = fa[e], bf = fb[e];
            #pragma unroll
            for (int j = 0; j < 8; ++j) {
                if (j < nm) {
                    if (a == mL[j]) { a = mW[j]; af = mWf[j]; }
                    if (b == mL[j]) { b = mW[j]; bf = mWf[j]; }
                }
            }
            if (a != b) {
                // reference: rv=root(v), rn=root(nb); n_wins=(f[rn]<f[rv])|(==&rn<rv)
                bool nw = (bf < af) || (bf == af && b < a);
                int w = nw ? b : a, l = nw ? a : b;
                float wf = nw ? bf : af;
                mL[nm] = l; mW[nm] = w; mWf[nm] = wf; mD[nm] = va[e];
                nm++;
            }
        }
        if (nm) {
            if (tid == 0) {
                #pragma unroll
                for (int j = 0; j < 8; ++j)
                    if (j < nm) pd[mL[j]] = (short)mD[j];
            }
            // parallel relabel to keep root[] pointing directly at roots
            for (int j2 = tid; j2 < N; j2 += 256) {
                int r = root[j2]; float rf = rootf[j2];
                #pragma unroll
                for (int j = 0; j < 8; ++j) {
                    if (j < nm && r == mL[j]) { r = mW[j]; rf = mWf[j]; }
                }
                root[j2] = (short)r; rootf[j2] = rf;
            }
            __syncthreads();
        }
    }
    if (tid == 0) {
        int vmax = (int)sidx_s[N - 1];
        int g = root[vmax];
        pd[g] = (short)vmax;
    }
    __syncthreads();

    // ---- landscapes: top-2 of tent functions per t ----
    const int wave = tid >> 6, lane = tid & 63;
    for (int t = wave; t < T; t += 4) {
        float tval = (t == T - 1) ? 80.0f : (1.0f + (float)t * (79.0f / 24.0f));
        float m1 = 0.f, m2 = 0.f;
        for (int i = lane; i < N; i += 64) {
            float bi = fv[i];
            float di = fv[(int)pd[i]];
            float tv = fminf(tval - bi, di - tval);
            tv = fmaxf(tv, 0.f);
            float lo = fminf(tv, m1);
            m1 = fmaxf(tv, m1);
            m2 = fmaxf(m2, lo);
        }
        #pragma unroll
        for (int off = 32; off > 0; off >>= 1) {
            float o1 = __shfl_down(m1, off, 64);
            float o2 = __shfl_down(m2, off, 64);
            float hi = fmaxf(m1, o1);
            float lo = fminf(m1, o1);
            m2 = fmaxf(fmaxf(m2, o2), lo);
            m1 = hi;
        }
        if (lane == 0) {
            feat[prob * 50 + t]     = m1;
            feat[prob * 50 + T + t] = m2;
        }
    }
}

// ============================================================
// Kernel 4: head.
// ============================================================
__global__ void head_kernel(const float* __restrict__ feat,
                            const float* __restrict__ wg1, const float* __restrict__ bg1,
                            const float* __restrict__ wg2, const float* __restrict__ bg2,
                            const float* __restrict__ fcw, const float* __restrict__ fcb,
                            float* __restrict__ out) {
    __shared__ float xc[B * 100];
    const int tid = threadIdx.x;
    for (int e = tid; e < B * 100; e += 256) {
        int b = e / 100, j = e % 100;
        const float* fp; const float* wrow; float bias;
        if (j < 50) { fp = feat + b * 50;       wrow = wg1 + j * 50;        bias = bg1[j]; }
        else        { fp = feat + (B + b) * 50; wrow = wg2 + (j - 50) * 50; bias = bg2[j - 50]; }
        float acc = bias;
        for (int q = 0; q < 50; ++q) acc += fp[q] * wrow[q];
        xc[e] = acc;
    }
    __syncthreads();
    for (int j = tid; j < 100; j += 256) {
        float s = 0.f;
        for (int b = 0; b < B; ++b) s += fabsf(xc[b * 100 + j]);
        out[320 + j] = s;
    }
    for (int e = tid; e < 320; e += 256) {
        int b = e / 10, o = e % 10;
        float acc = fcb[o];
        for (int j = 0; j < 100; ++j)
            acc += fmaxf(xc[b * 100 + j], 0.f) * fcw[o * 100 + j];
        out[e] = acc;
    }
}

extern "C" void kernel_launch(void* const* d_in, const int* in_sizes, int n_in,
                              void* d_out, int out_size, void* d_ws, size_t ws_size,
                              hipStream_t stream) {
    (void)in_sizes; (void)n_in; (void)out_size; (void)ws_size;
    const float* x   = (const float*)d_in[0];
    const float* wg1 = (const float*)d_in[1];
    const float* bg1 = (const float*)d_in[2];
    const float* wg2 = (const float*)d_in[3];
    const float* bg2 = (const float*)d_in[4];
    const float* fcw = (const float*)d_in[5];
    const float* fcb = (const float*)d_in[6];
    float* out = (float*)d_out;

    char* ws = (char*)d_ws;
    float*          d2s  = (float*)ws;                                   // N*N f32
    unsigned short* sidx = (unsigned short*)(ws + (size_t)N * N * 4);    // N*N u16
    float*          f    = (float*)(ws + (size_t)N * N * 6);             // 2*B*N f32
    float*          feat = f + 2 * B * N;                                // 2*B*50 f32

    sort_d2_kernel<<<dim3(N), dim3(256), 0, stream>>>(d2s, sidx);
    dtm_kernel<<<dim3(64), dim3(256), 0, stream>>>(x, d2s, sidx, f);
    ph0_kernel<<<dim3(64), dim3(256), 0, stream>>>(f, feat);
    head_kernel<<<dim3(1), dim3(256), 0, stream>>>(feat, wg1, bg1, wg2, bg2, fcw, fcb, out);
}

// Round 3
// 620.851 us; speedup vs baseline: 1.3932x; 1.2545x over previous
//
#include <hip/hip_runtime.h>
#include <math.h>

#define H 28
#define N 784
#define B 32
#define T 25
#define NPAD 1024
#define CH 16

// ---- numpy linspace replication (float64) ----
__device__ __forceinline__ double coord_r(int i) {
    if (i == H - 1) return 0.0;
    return 224.0 + (double)i * ((0.0 - 224.0) / 27.0);
}
__device__ __forceinline__ double coord_c(int j) {
    if (j == H - 1) return 224.0;
    return (double)j * (224.0 / 27.0);
}

// ============================================================
// Kernel 1: per-row sort of squared distances (f64, bitonic in LDS).
// Output transposed: d2s_t[k*N + i], sidx_t[k*N + i].
// ============================================================
__global__ void sort_d2_kernel(float* __restrict__ d2s_t,
                               unsigned short* __restrict__ sidx_t) {
    __shared__ double key[NPAD];
    __shared__ int    idx[NPAD];
    const int i   = blockIdx.x;
    const int tid = threadIdx.x;
    const int ri = i / H, ci = i % H;
    const double rri = coord_r(ri), cci = coord_c(ci);
    for (int j = tid; j < NPAD; j += 256) {
        if (j < N) {
            int rj = j / H, cj = j % H;
            double dr = rri - coord_r(rj);
            double dc = cci - coord_c(cj);
            key[j] = dr * dr + dc * dc;
        } else {
            key[j] = 1.0e300;
        }
        idx[j] = j;
    }
    __syncthreads();
    for (int k = 2; k <= NPAD; k <<= 1) {
        for (int j = k >> 1; j > 0; j >>= 1) {
            for (int a = tid; a < NPAD; a += 256) {
                int b = a ^ j;
                if (b > a) {
                    double ka = key[a], kb = key[b];
                    int    ia = idx[a], ib = idx[b];
                    bool gt = (ka > kb) || (ka == kb && ia > ib);
                    if (gt == ((a & k) == 0)) {
                        key[a] = kb; key[b] = ka;
                        idx[a] = ib; idx[b] = ia;
                    }
                }
            }
            __syncthreads();
        }
    }
    for (int j = tid; j < N; j += 256) {
        d2s_t[j * N + i]  = (float)key[j];
        sidx_t[j * N + i] = (unsigned short)idx[j];
    }
}

// ============================================================
// Kernel 2: fused DTM + PH0 + landscapes. One block per (m0, b).
// ============================================================
__global__ __launch_bounds__(256) void dtm_ph0_kernel(
        const float* __restrict__ x,
        const float* __restrict__ d2s_t,
        const unsigned short* __restrict__ sidx_t,
        float* __restrict__ feat) {
    __shared__ float lw[N];
    __shared__ float red[256];
    __shared__ float fv[N];
    __shared__ float skey[NPAD];
    __shared__ short sidx_s[NPAD];
    __shared__ short rank_[N];
    __shared__ float2 rr[NPAD];      // .x = f[root], .y = root index (int bits)
    __shared__ short pd[N];
    __shared__ unsigned short ev[1536];
    __shared__ unsigned short enb[1536];
    __shared__ int tcnt[256];

    const int prob = blockIdx.x;          // mi*32 + b
    const int b  = prob & 31;
    const int mi = prob >> 5;
    const float m0 = mi ? 0.2f : 0.05f;
    const int tid = threadIdx.x;

    // ---- load weights + total mass ----
    float s = 0.f;
    for (int i = tid; i < N; i += 256) { float v = x[b * N + i]; lw[i] = v; s += v; }
    red[tid] = s;
    __syncthreads();
    for (int off = 128; off > 0; off >>= 1) {
        if (tid < off) red[tid] += red[tid + off];
        __syncthreads();
    }
    const float m0W = m0 * red[0];

    // ---- DTM: chunked early-exit walk (arithmetic identical to scalar walk) ----
    for (int i = tid; i < N; i += 256) {
        float cum = 0.f, acc = 0.f;
        for (int k0 = 0; k0 < N; k0 += CH) {
            float d2c[CH]; int idc[CH];
            #pragma unroll
            for (int c = 0; c < CH; ++c) {
                d2c[c] = d2s_t[(k0 + c) * N + i];
                idc[c] = sidx_t[(k0 + c) * N + i];
            }
            float swc[CH];
            #pragma unroll
            for (int c = 0; c < CH; ++c) swc[c] = lw[idc[c]];
            #pragma unroll
            for (int c = 0; c < CH; ++c) {
                float rem = m0W - cum;
                float contrib = fminf(fmaxf(rem, 0.f), swc[c]);
                acc += contrib * d2c[c];
                cum += swc[c];
            }
            if (cum >= m0W) break;   // all later contribs are exactly 0
        }
        fv[i] = sqrtf(fmaxf(acc / m0W, 1e-12f));
    }
    __syncthreads();

    // ---- stable bitonic argsort ascending by (f, idx) ----
    for (int j = tid; j < NPAD; j += 256) {
        skey[j]  = (j < N) ? fv[j] : 3.0e38f;
        sidx_s[j] = (short)j;
    }
    __syncthreads();
    for (int k = 2; k <= NPAD; k <<= 1) {
        for (int j = k >> 1; j > 0; j >>= 1) {
            for (int a = tid; a < NPAD; a += 256) {
                int b2 = a ^ j;
                if (b2 > a) {
                    float ka = skey[a], kb = skey[b2];
                    short ia = sidx_s[a], ib = sidx_s[b2];
                    bool gt = (ka > kb) || (ka == kb && ia > ib);
                    if (gt == ((a & k) == 0)) {
                        skey[a] = kb; skey[b2] = ka;
                        sidx_s[a] = ib; sidx_s[b2] = ia;
                    }
                }
            }
            __syncthreads();
        }
    }
    // ---- init rank / roots / pd (rr padded to 1024 with inert entries) ----
    for (int j = tid; j < NPAD; j += 256) {
        if (j < N) {
            int v = sidx_s[j];
            rank_[v] = (short)j;
            rr[j] = make_float2(fv[j], __int_as_float(j));
            pd[j] = (short)j;
        } else {
            rr[j] = make_float2(3.0e38f, __int_as_float(j));
        }
    }
    __syncthreads();

    // ---- build ordered compact edge list: key = (rank(v), nbr slot) ----
    int cnt = 0;
    #pragma unroll
    for (int rrk = 0; rrk < 4; ++rrk) {
        int r = tid * 4 + rrk;
        if (r < N) {
            int v = sidx_s[r];
            int row = v / H, col = v % H;
            if (row > 0     && (int)rank_[v - H] < r) cnt++;
            if (row < H - 1 && (int)rank_[v + H] < r) cnt++;
            if (col > 0     && (int)rank_[v - 1] < r) cnt++;
            if (col < H - 1 && (int)rank_[v + 1] < r) cnt++;
        }
    }
    tcnt[tid] = cnt;
    __syncthreads();
    for (int off = 1; off < 256; off <<= 1) {
        int v = tcnt[tid];
        if (tid >= off) v += tcnt[tid - off];
        __syncthreads();
        tcnt[tid] = v;
        __syncthreads();
    }
    const int m = tcnt[255];
    int pos = tcnt[tid] - cnt;
    #pragma unroll
    for (int rrk = 0; rrk < 4; ++rrk) {
        int r = tid * 4 + rrk;
        if (r < N) {
            int v = sidx_s[r];
            int row = v / H, col = v % H;
            int nbs[4] = { v - H, v + H, v - 1, v + 1 };
            bool val[4] = { row > 0, row < H - 1, col > 0, col < H - 1 };
            #pragma unroll
            for (int k4 = 0; k4 < 4; ++k4) {
                if (val[k4] && (int)rank_[nbs[k4]] < r) {
                    ev[pos]  = (unsigned short)v;
                    enb[pos] = (unsigned short)nbs[k4];
                    pos++;
                }
            }
        }
    }
    __syncthreads();

    // ---- speculative batched Kruskal, static-index records only ----
    const int nbatch = (m + 7) >> 3;
    int va[8], na[8];
    #pragma unroll
    for (int e = 0; e < 8; ++e) {
        bool ok = e < m;
        va[e] = ok ? (int)ev[e]  : 0;
        na[e] = ok ? (int)enb[e] : 0;
    }
    for (int bi = 0; bi < nbatch; ++bi) {
        const int base = bi * 8;
        // gather roots of this batch's endpoints (broadcast reads)
        float2 ga[8], gb[8];
        #pragma unroll
        for (int e = 0; e < 8; ++e) { ga[e] = rr[va[e]]; gb[e] = rr[na[e]]; }
        // relabel slot reads (addresses static, issued early)
        float2 s0 = rr[tid], s1 = rr[tid + 256], s2 = rr[tid + 512], s3 = rr[tid + 768];
        // prefetch next batch endpoints
        int nva[8], nna[8];
        #pragma unroll
        for (int e = 0; e < 8; ++e) {
            int idx = base + 8 + e;
            bool ok = idx < m;
            nva[e] = ok ? (int)ev[idx]  : 0;
            nna[e] = ok ? (int)enb[idx] : 0;
        }
        // in-register sequential resolution; all indices literal after unroll
        int L[8], W[8]; float WF[8]; bool V[8];
        #pragma unroll
        for (int e = 0; e < 8; ++e) {
            int a = __float_as_int(ga[e].y); float af = ga[e].x;
            int bb = __float_as_int(gb[e].y); float bf = gb[e].x;
            #pragma unroll
            for (int j = 0; j < e; ++j) {
                bool ha = V[j] && (a == L[j]);
                a  = ha ? W[j]  : a;
                af = ha ? WF[j] : af;
                bool hb = V[j] && (bb == L[j]);
                bb = hb ? W[j]  : bb;
                bf = hb ? WF[j] : bf;
            }
            bool nw = (bf < af) || (bf == af && bb < a);
            V[e]  = (base + e < m) && (a != bb);
            W[e]  = nw ? bb : a;
            L[e]  = nw ? a  : bb;
            WF[e] = nw ? bf : af;
        }
        bool any = false;
        #pragma unroll
        for (int e = 0; e < 8; ++e) any |= V[e];
        if (any) {   // uniform across all threads
            __syncthreads();     // all gather-reads done before any write
            if (tid == 0) {
                #pragma unroll
                for (int e = 0; e < 8; ++e)
                    if (V[e]) pd[L[e]] = (short)va[e];
            }
            // apply merges (in order) to the 4 owned slots, write back
            #pragma unroll
            for (int slot = 0; slot < 4; ++slot) {
                float2 sv = slot == 0 ? s0 : slot == 1 ? s1 : slot == 2 ? s2 : s3;
                int r = __float_as_int(sv.y); float rf = sv.x;
                #pragma unroll
                for (int e = 0; e < 8; ++e) {
                    bool hit = V[e] && (r == L[e]);
                    r  = hit ? W[e]  : r;
                    rf = hit ? WF[e] : rf;
                }
                rr[tid + slot * 256] = make_float2(rf, __int_as_float(r));
            }
            __syncthreads();
        }
        #pragma unroll
        for (int e = 0; e < 8; ++e) { va[e] = nva[e]; na[e] = nna[e]; }
    }
    __syncthreads();
    if (tid == 0) {
        int vmax = (int)sidx_s[N - 1];
        int g = __float_as_int(rr[vmax].y);
        pd[g] = (short)vmax;
    }
    __syncthreads();

    // ---- landscapes: top-2 of tent functions per t ----
    const int wave = tid >> 6, lane = tid & 63;
    for (int t = wave; t < T; t += 4) {
        float tval = (t == T - 1) ? 80.0f : (1.0f + (float)t * (79.0f / 24.0f));
        float m1 = 0.f, m2 = 0.f;
        for (int i = lane; i < N; i += 64) {
            float bi = fv[i];
            float di = fv[(int)pd[i]];
            float tv = fminf(tval - bi, di - tval);
            tv = fmaxf(tv, 0.f);
            float lo = fminf(tv, m1);
            m1 = fmaxf(tv, m1);
            m2 = fmaxf(m2, lo);
        }
        #pragma unroll
        for (int off = 32; off > 0; off >>= 1) {
            float o1 = __shfl_down(m1, off, 64);
            float o2 = __shfl_down(m2, off, 64);
            float hi = fmaxf(m1, o1);
            float lo = fminf(m1, o1);
            m2 = fmaxf(fmaxf(m2, o2), lo);
            m1 = hi;
        }
        if (lane == 0) {
            feat[prob * 50 + t]     = m1;
            feat[prob * 50 + T + t] = m2;
        }
    }
}

// ============================================================
// Kernel 3: head.
// ============================================================
__global__ void head_kernel(const float* __restrict__ feat,
                            const float* __restrict__ wg1, const float* __restrict__ bg1,
                            const float* __restrict__ wg2, const float* __restrict__ bg2,
                            const float* __restrict__ fcw, const float* __restrict__ fcb,
                            float* __restrict__ out) {
    __shared__ float xc[B * 100];
    const int tid = threadIdx.x;
    for (int e = tid; e < B * 100; e += 256) {
        int b = e / 100, j = e % 100;
        const float* fp; const float* wrow; float bias;
        if (j < 50) { fp = feat + b * 50;       wrow = wg1 + j * 50;        bias = bg1[j]; }
        else        { fp = feat + (B + b) * 50; wrow = wg2 + (j - 50) * 50; bias = bg2[j - 50]; }
        float acc = bias;
        for (int q = 0; q < 50; ++q) acc += fp[q] * wrow[q];
        xc[e] = acc;
    }
    __syncthreads();
    for (int j = tid; j < 100; j += 256) {
        float s = 0.f;
        for (int b = 0; b < B; ++b) s += fabsf(xc[b * 100 + j]);
        out[320 + j] = s;
    }
    for (int e = tid; e < 320; e += 256) {
        int b = e / 10, o = e % 10;
        float acc = fcb[o];
        for (int j = 0; j < 100; ++j)
            acc += fmaxf(xc[b * 100 + j], 0.f) * fcw[o * 100 + j];
        out[e] = acc;
    }
}

extern "C" void kernel_launch(void* const* d_in, const int* in_sizes, int n_in,
                              void* d_out, int out_size, void* d_ws, size_t ws_size,
                              hipStream_t stream) {
    (void)in_sizes; (void)n_in; (void)out_size; (void)ws_size;
    const float* x   = (const float*)d_in[0];
    const float* wg1 = (const float*)d_in[1];
    const float* bg1 = (const float*)d_in[2];
    const float* wg2 = (const float*)d_in[3];
    const float* bg2 = (const float*)d_in[4];
    const float* fcw = (const float*)d_in[5];
    const float* fcb = (const float*)d_in[6];
    float* out = (float*)d_out;

    char* ws = (char*)d_ws;
    float*          d2s  = (float*)ws;                                   // N*N f32
    unsigned short* sidx = (unsigned short*)(ws + (size_t)N * N * 4);    // N*N u16
    float*          feat = (float*)(ws + (size_t)N * N * 6);             // 2*B*50 f32

    sort_d2_kernel<<<dim3(N), dim3(256), 0, stream>>>(d2s, sidx);
    dtm_ph0_kernel<<<dim3(64), dim3(256), 0, stream>>>(x, d2s, sidx, feat);
    head_kernel<<<dim3(1), dim3(256), 0, stream>>>(feat, wg1, bg1, wg2, bg2, fcw, fcb, out);
}

// Round 4
// 499.621 us; speedup vs baseline: 1.7313x; 1.2426x over previous
//
#include <hip/hip_runtime.h>
#include <math.h>

#define H 28
#define N 784
#define B 32
#define T 25
#define NPAD 1024
#define CH 16
#define MEDGE 1536
#define NBATCH 192

// ---- numpy linspace replication (float64) ----
__device__ __forceinline__ double coord_r(int i) {
    if (i == H - 1) return 0.0;
    return 224.0 + (double)i * ((0.0 - 224.0) / 27.0);
}
__device__ __forceinline__ double coord_c(int j) {
    if (j == H - 1) return 224.0;
    return (double)j * (224.0 / 27.0);
}

// ============================================================
// K1: per-row sort by u32 key (int_d2<<10 | j). Integer lattice d2
// has min gap 1 unit = 68.8 in f64 scale >> any rounding; tie-group
// contribution sums are order-invariant -> ordering equivalent to ref.
// ============================================================
__global__ void sort_d2_kernel(float* __restrict__ d2s_t,
                               unsigned short* __restrict__ sidx_t) {
    __shared__ unsigned key[NPAD];
    const int i = blockIdx.x, tid = threadIdx.x;
    const int ri = i / H, ci = i % H;
    for (int j = tid; j < NPAD; j += 256) {
        if (j < N) {
            int dr = ri - j / H, dc = ci - j % H;
            key[j] = ((unsigned)(dr * dr + dc * dc) << 10) | (unsigned)j;
        } else {
            key[j] = 0xFFFFFFFFu;
        }
    }
    __syncthreads();
    for (int k = 2; k <= NPAD; k <<= 1) {
        for (int j = k >> 1; j > 0; j >>= 1) {
            for (int a = tid; a < NPAD; a += 256) {
                int b = a ^ j;
                if (b > a) {
                    unsigned ka = key[a], kb = key[b];
                    if ((ka > kb) == ((a & k) == 0)) { key[a] = kb; key[b] = ka; }
                }
            }
            __syncthreads();
        }
    }
    const double rri = coord_r(ri), cci = coord_c(ci);
    for (int j = tid; j < N; j += 256) {
        int jj = (int)(key[j] & 1023u);
        double dr = rri - coord_r(jj / H);
        double dc = cci - coord_c(jj % H);
        d2s_t[j * N + i]  = (float)(dr * dr + dc * dc);
        sidx_t[j * N + i] = (unsigned short)jj;
    }
}

// ============================================================
// K2: DTM. 1024 threads, one sorted-walk per thread, early exit.
// ============================================================
__global__ __launch_bounds__(1024) void dtm_kernel(
        const float* __restrict__ x,
        const float* __restrict__ d2s_t,
        const unsigned short* __restrict__ sidx_t,
        float* __restrict__ fv_g) {
    __shared__ float lw[N];
    __shared__ float red[1024];
    const int prob = blockIdx.x;
    const int b  = prob & 31;
    const int mi = prob >> 5;
    const float m0 = mi ? 0.2f : 0.05f;
    const int tid = threadIdx.x;
    float s = 0.f;
    if (tid < N) { float v = x[b * N + tid]; lw[tid] = v; s = v; }
    red[tid] = s;
    __syncthreads();
    for (int off = 512; off > 0; off >>= 1) {
        if (tid < off) red[tid] += red[tid + off];
        __syncthreads();
    }
    const float m0W = m0 * red[0];
    if (tid < N) {
        const int i = tid;
        float cum = 0.f, acc = 0.f;
        for (int k0 = 0; k0 < N; k0 += CH) {
            float d2c[CH]; int idc[CH];
            #pragma unroll
            for (int c = 0; c < CH; ++c) {
                d2c[c] = d2s_t[(k0 + c) * N + i];
                idc[c] = sidx_t[(k0 + c) * N + i];
            }
            float swc[CH];
            #pragma unroll
            for (int c = 0; c < CH; ++c) swc[c] = lw[idc[c]];
            #pragma unroll
            for (int c = 0; c < CH; ++c) {
                float rem = m0W - cum;
                float contrib = fminf(fmaxf(rem, 0.f), swc[c]);
                acc += contrib * d2c[c];
                cum += swc[c];
            }
            if (cum >= m0W) break;   // all later contribs are exactly 0
        }
        fv_g[prob * N + i] = sqrtf(fmaxf(acc / m0W, 1e-12f));
    }
}

// ============================================================
// K3: stable argsort of f + ordered edge list (packed v|(nb<<16)),
// padded to MEDGE with inert (0,0) edges. Also vmax per problem.
// ============================================================
__global__ __launch_bounds__(512) void sort_edges_kernel(
        const float* __restrict__ fv_g,
        unsigned* __restrict__ ev32_g,
        int* __restrict__ vmax_g) {
    __shared__ float skey[NPAD];
    __shared__ short sidx_s[NPAD];
    __shared__ short rank_[N];
    __shared__ int tcnt[512];
    const int prob = blockIdx.x, tid = threadIdx.x;
    for (int j = tid; j < NPAD; j += 512) {
        skey[j]  = (j < N) ? fv_g[prob * N + j] : 3.0e38f;
        sidx_s[j] = (short)j;
    }
    __syncthreads();
    for (int k = 2; k <= NPAD; k <<= 1) {
        for (int j = k >> 1; j > 0; j >>= 1) {
            for (int a = tid; a < NPAD; a += 512) {
                int b2 = a ^ j;
                if (b2 > a) {
                    float ka = skey[a], kb = skey[b2];
                    short ia = sidx_s[a], ib = sidx_s[b2];
                    bool gt = (ka > kb) || (ka == kb && ia > ib);
                    if (gt == ((a & k) == 0)) {
                        skey[a] = kb; skey[b2] = ka;
                        sidx_s[a] = ib; sidx_s[b2] = ia;
                    }
                }
            }
            __syncthreads();
        }
    }
    for (int j = tid; j < N; j += 512) rank_[sidx_s[j]] = (short)j;
    __syncthreads();
    int cnt = 0;
    #pragma unroll
    for (int rr2 = 0; rr2 < 2; ++rr2) {
        int r = tid * 2 + rr2;
        if (r < N) {
            int v = sidx_s[r];
            int row = v / H, col = v % H;
            if (row > 0     && (int)rank_[v - H] < r) cnt++;
            if (row < H - 1 && (int)rank_[v + H] < r) cnt++;
            if (col > 0     && (int)rank_[v - 1] < r) cnt++;
            if (col < H - 1 && (int)rank_[v + 1] < r) cnt++;
        }
    }
    tcnt[tid] = cnt;
    __syncthreads();
    for (int off = 1; off < 512; off <<= 1) {
        int v = tcnt[tid];
        int add = (tid >= off) ? tcnt[tid - off] : 0;
        __syncthreads();
        tcnt[tid] = v + add;
        __syncthreads();
    }
    const int m = tcnt[511];
    int pos = tcnt[tid] - cnt;
    #pragma unroll
    for (int rr2 = 0; rr2 < 2; ++rr2) {
        int r = tid * 2 + rr2;
        if (r < N) {
            int v = sidx_s[r];
            int row = v / H, col = v % H;
            int nbs[4] = { v - H, v + H, v - 1, v + 1 };
            bool val[4] = { row > 0, row < H - 1, col > 0, col < H - 1 };
            #pragma unroll
            for (int k4 = 0; k4 < 4; ++k4) {
                if (val[k4] && (int)rank_[nbs[k4]] < r) {
                    ev32_g[prob * MEDGE + pos] = (unsigned)v | ((unsigned)nbs[k4] << 16);
                    pos++;
                }
            }
        }
    }
    for (int j = m + tid; j < MEDGE; j += 512) ev32_g[prob * MEDGE + j] = 0u;  // inert pad
    if (tid == 0) vmax_g[prob] = (int)sidx_s[N - 1];
}

// ============================================================
// K4: speculative batched Kruskal (8 edges/batch, static indices),
// direct-root labels rr = (f[root], root) + parallel relabel.
// ============================================================
__global__ __launch_bounds__(256, 1) void kruskal_kernel(
        const float* __restrict__ fv_g,
        const unsigned* __restrict__ ev32_g,
        const int* __restrict__ vmax_g,
        short* __restrict__ pd_g) {
    __shared__ float2 rr[NPAD];
    __shared__ short pd[N];
    __shared__ unsigned ed[MEDGE];
    const int prob = blockIdx.x, tid = threadIdx.x;
    for (int j = tid; j < NPAD; j += 256)
        rr[j] = make_float2((j < N) ? fv_g[prob * N + j] : 3.0e38f, __int_as_float(j));
    for (int j = tid; j < MEDGE; j += 256) ed[j] = ev32_g[prob * MEDGE + j];
    for (int j = tid; j < N; j += 256) pd[j] = (short)j;
    __syncthreads();

    unsigned cur[8];
    #pragma unroll
    for (int e = 0; e < 8; ++e) cur[e] = ed[e];
    for (int bi = 0; bi < NBATCH; ++bi) {
        const int base = bi * 8;
        int va[8], na[8];
        #pragma unroll
        for (int e = 0; e < 8; ++e) { va[e] = (int)(cur[e] & 0xFFFFu); na[e] = (int)(cur[e] >> 16); }
        float2 ga[8], gb[8];
        #pragma unroll
        for (int e = 0; e < 8; ++e) { ga[e] = rr[va[e]]; gb[e] = rr[na[e]]; }
        float2 s0 = rr[tid], s1 = rr[tid + 256], s2 = rr[tid + 512], s3 = rr[tid + 768];
        unsigned nxt[8];
        #pragma unroll
        for (int e = 0; e < 8; ++e) nxt[e] = (bi + 1 < NBATCH) ? ed[base + 8 + e] : 0u;
        int L[8], W[8]; float WF[8]; bool V[8];
        #pragma unroll
        for (int e = 0; e < 8; ++e) {
            int a = __float_as_int(ga[e].y); float af = ga[e].x;
            int bb = __float_as_int(gb[e].y); float bf = gb[e].x;
            #pragma unroll
            for (int j = 0; j < e; ++j) {
                bool ha = V[j] && (a == L[j]);
                a  = ha ? W[j]  : a;
                af = ha ? WF[j] : af;
                bool hb = V[j] && (bb == L[j]);
                bb = hb ? W[j]  : bb;
                bf = hb ? WF[j] : bf;
            }
            bool nw = (bf < af) || (bf == af && bb < a);
            V[e]  = (a != bb);
            W[e]  = nw ? bb : a;
            L[e]  = nw ? a  : bb;
            WF[e] = nw ? bf : af;
        }
        bool any = false;
        #pragma unroll
        for (int e = 0; e < 8; ++e) any |= V[e];
        if (any) {                 // uniform branch
            __syncthreads();       // all gather-reads before any write
            if (tid == 0) {
                #pragma unroll
                for (int e = 0; e < 8; ++e)
                    if (V[e]) pd[L[e]] = (short)va[e];
            }
            #pragma unroll
            for (int slot = 0; slot < 4; ++slot) {
                float2 sv = slot == 0 ? s0 : slot == 1 ? s1 : slot == 2 ? s2 : s3;
                int r = __float_as_int(sv.y); float rf = sv.x;
                #pragma unroll
                for (int e = 0; e < 8; ++e) {
                    bool hit = V[e] && (r == L[e]);
                    r  = hit ? W[e]  : r;
                    rf = hit ? WF[e] : rf;
                }
                rr[tid + slot * 256] = make_float2(rf, __int_as_float(r));
            }
            __syncthreads();
        }
        #pragma unroll
        for (int e = 0; e < 8; ++e) cur[e] = nxt[e];
    }
    __syncthreads();
    if (tid == 0) {
        int vmax = vmax_g[prob];
        int g = __float_as_int(rr[vmax].y);
        pd[g] = (short)vmax;
    }
    __syncthreads();
    for (int j = tid; j < N; j += 256) pd_g[prob * N + j] = pd[j];
}

// ============================================================
// K5: landscapes top-2 per t.
// ============================================================
__global__ __launch_bounds__(256) void land_kernel(
        const float* __restrict__ fv_g,
        const short* __restrict__ pd_g,
        float* __restrict__ feat) {
    __shared__ float fv[N];
    __shared__ short pd[N];
    const int prob = blockIdx.x, tid = threadIdx.x;
    for (int j = tid; j < N; j += 256) { fv[j] = fv_g[prob * N + j]; pd[j] = pd_g[prob * N + j]; }
    __syncthreads();
    const int wave = tid >> 6, lane = tid & 63;
    for (int t = wave; t < T; t += 4) {
        float tval = (t == T - 1) ? 80.0f : (1.0f + (float)t * (79.0f / 24.0f));
        float m1 = 0.f, m2 = 0.f;
        for (int i = lane; i < N; i += 64) {
            float bi = fv[i];
            float di = fv[(int)pd[i]];
            float tv = fminf(tval - bi, di - tval);
            tv = fmaxf(tv, 0.f);
            float lo = fminf(tv, m1);
            m1 = fmaxf(tv, m1);
            m2 = fmaxf(m2, lo);
        }
        #pragma unroll
        for (int off = 32; off > 0; off >>= 1) {
            float o1 = __shfl_down(m1, off, 64);
            float o2 = __shfl_down(m2, off, 64);
            float hi = fmaxf(m1, o1);
            float lo = fminf(m1, o1);
            m2 = fmaxf(fmaxf(m2, o2), lo);
            m1 = hi;
        }
        if (lane == 0) {
            feat[prob * 50 + t]     = m1;
            feat[prob * 50 + T + t] = m2;
        }
    }
}

// ============================================================
// K6: head.
// ============================================================
__global__ void head_kernel(const float* __restrict__ feat,
                            const float* __restrict__ wg1, const float* __restrict__ bg1,
                            const float* __restrict__ wg2, const float* __restrict__ bg2,
                            const float* __restrict__ fcw, const float* __restrict__ fcb,
                            float* __restrict__ out) {
    __shared__ float xc[B * 100];
    const int tid = threadIdx.x;
    for (int e = tid; e < B * 100; e += 256) {
        int b = e / 100, j = e % 100;
        const float* fp; const float* wrow; float bias;
        if (j < 50) { fp = feat + b * 50;       wrow = wg1 + j * 50;        bias = bg1[j]; }
        else        { fp = feat + (B + b) * 50; wrow = wg2 + (j - 50) * 50; bias = bg2[j - 50]; }
        float acc = bias;
        for (int q = 0; q < 50; ++q) acc += fp[q] * wrow[q];
        xc[e] = acc;
    }
    __syncthreads();
    for (int j = tid; j < 100; j += 256) {
        float s = 0.f;
        for (int b = 0; b < B; ++b) s += fabsf(xc[b * 100 + j]);
        out[320 + j] = s;
    }
    for (int e = tid; e < 320; e += 256) {
        int b = e / 10, o = e % 10;
        float acc = fcb[o];
        for (int j = 0; j < 100; ++j)
            acc += fmaxf(xc[b * 100 + j], 0.f) * fcw[o * 100 + j];
        out[e] = acc;
    }
}

extern "C" void kernel_launch(void* const* d_in, const int* in_sizes, int n_in,
                              void* d_out, int out_size, void* d_ws, size_t ws_size,
                              hipStream_t stream) {
    (void)in_sizes; (void)n_in; (void)out_size; (void)ws_size;
    const float* x   = (const float*)d_in[0];
    const float* wg1 = (const float*)d_in[1];
    const float* bg1 = (const float*)d_in[2];
    const float* wg2 = (const float*)d_in[3];
    const float* bg2 = (const float*)d_in[4];
    const float* fcw = (const float*)d_in[5];
    const float* fcb = (const float*)d_in[6];
    float* out = (float*)d_out;

    char* ws = (char*)d_ws;
    // d2s_t/sidx_t live until dtm completes; ev32/pd/vmax/feat reuse that region after.
    float*          d2s   = (float*)ws;                                  // [0, 2.458M)
    unsigned short* sidxt = (unsigned short*)(ws + (size_t)N * N * 4);   // [2.458M, 3.688M)
    float*          fv_g  = (float*)(ws + (size_t)N * N * 6);            // 64*784 f32 (live across)
    unsigned*       ev32  = (unsigned*)ws;                               // 64*1536 u32 (overwrites d2s)
    short*          pd_g  = (short*)(ws + 1600 * 1024);                  // 64*784 i16
    int*            vmaxg = (int*)(ws + 2000 * 1024);                    // 64 i32
    float*          feat  = (float*)(ws + 2100 * 1024);                  // 64*50 f32

    sort_d2_kernel<<<dim3(N), dim3(256), 0, stream>>>(d2s, sidxt);
    dtm_kernel<<<dim3(64), dim3(1024), 0, stream>>>(x, d2s, sidxt, fv_g);
    sort_edges_kernel<<<dim3(64), dim3(512), 0, stream>>>(fv_g, ev32, vmaxg);
    kruskal_kernel<<<dim3(64), dim3(256), 0, stream>>>(fv_g, ev32, vmaxg, pd_g);
    land_kernel<<<dim3(64), dim3(256), 0, stream>>>(fv_g, pd_g, feat);
    head_kernel<<<dim3(1), dim3(256), 0, stream>>>(feat, wg1, bg1, wg2, bg2, fcw, fcb, out);
}